// Round 3
// baseline (3363.055 us; speedup 1.0000x reference)
//
#include <hip/hip_runtime.h>
#include <math.h>

// ===== Per-XCD privatized path =====
// ws layout (needs 10*N floats = 40 MB):
//   [0, 8N)  copies: 8 per-XCD accumulator copies (float)
//   [8N,9N)  s    (float)
//   [9N,10N) dinv (float)
//
// Phase A: deg into per-XCD copies (workgroup-scope atomics, stay in XCD L2)
// Phase B: reduce copies -> dinv, s; re-zero copies
// Phase C: scatter s[src] into per-XCD copies
// Phase D: reduce copies + self-loop -> sigmoid -> out
// Cross-XCD visibility comes from end-of-kernel L2 writeback (kernel boundary).

typedef int  iv4 __attribute__((ext_vector_type(4)));   // clang ext-vector: OK for nontemporal builtins

__device__ __forceinline__ int get_xcc() {
    int x;
    asm volatile("s_getreg_b32 %0, hwreg(HW_REG_XCC_ID)" : "=s"(x));
    return x & 7;
}

__device__ __forceinline__ void atomic_add_wg(float* p, float v) {
    __hip_atomic_fetch_add(p, v, __ATOMIC_RELAXED, __HIP_MEMORY_SCOPE_WORKGROUP);
}

__global__ void zero_f_kernel(float* __restrict__ p, int n) {
    int i = blockIdx.x * blockDim.x + threadIdx.x;
    if (i < n) p[i] = 0.0f;
}

__global__ void deg_priv_kernel(const int* __restrict__ dst, float* __restrict__ copies,
                                int E, int N) {
    int xcc = get_xcc();
    float* my = copies + (size_t)xcc * N;
    int i = (blockIdx.x * blockDim.x + threadIdx.x) * 4;
    if (i + 3 < E) {
        iv4 d = __builtin_nontemporal_load(reinterpret_cast<const iv4*>(dst + i));
        atomic_add_wg(&my[d.x], 1.0f);
        atomic_add_wg(&my[d.y], 1.0f);
        atomic_add_wg(&my[d.z], 1.0f);
        atomic_add_wg(&my[d.w], 1.0f);
    } else {
        for (int k = i; k < E; ++k) atomic_add_wg(&my[dst[k]], 1.0f);
    }
}

// deg = 1 + sum(copies); dinv = rsqrt(deg); s = x*W*dinv; copies reset to 0.
__global__ void node_reduce_kernel(const float* __restrict__ x, const float* __restrict__ W,
                                   float* __restrict__ copies,
                                   float* __restrict__ s, float* __restrict__ dinv, int N) {
    int i = blockIdx.x * blockDim.x + threadIdx.x;
    if (i < N) {
        float deg = 1.0f;
#pragma unroll
        for (int c = 0; c < 8; ++c) {
            deg += copies[(size_t)c * N + i];
            copies[(size_t)c * N + i] = 0.0f;
        }
        float di = rsqrtf(deg);
        dinv[i] = di;
        s[i] = x[i] * W[0] * di;
    }
}

__global__ void scatter_priv_kernel(const int* __restrict__ src, const int* __restrict__ dst,
                                    const float* __restrict__ s, float* __restrict__ copies,
                                    int E, int N) {
    int xcc = get_xcc();
    float* my = copies + (size_t)xcc * N;
    int i = (blockIdx.x * blockDim.x + threadIdx.x) * 4;
    if (i + 3 < E) {
        iv4 sv = __builtin_nontemporal_load(reinterpret_cast<const iv4*>(src + i));
        iv4 dv = __builtin_nontemporal_load(reinterpret_cast<const iv4*>(dst + i));
        float a = s[sv.x];
        float b = s[sv.y];
        float c = s[sv.z];
        float d = s[sv.w];
        atomic_add_wg(&my[dv.x], a);
        atomic_add_wg(&my[dv.y], b);
        atomic_add_wg(&my[dv.z], c);
        atomic_add_wg(&my[dv.w], d);
    } else {
        for (int k = i; k < E; ++k) atomic_add_wg(&my[dst[k]], s[src[k]]);
    }
}

__global__ void out_reduce_kernel(const float* __restrict__ copies, const float* __restrict__ s,
                                  const float* __restrict__ dinv, const float* __restrict__ b,
                                  float* __restrict__ out, int N) {
    int i = blockIdx.x * blockDim.x + threadIdx.x;
    if (i < N) {
        float acc = s[i];  // self-loop
#pragma unroll
        for (int c = 0; c < 8; ++c) acc += copies[(size_t)c * N + i];
        float z = dinv[i] * acc + b[0];
        out[i] = 1.0f / (1.0f + expf(-z));
    }
}

// ===== Fallback path (round-0, agent-scope atomics) =====
__global__ void zero_kernel(int* __restrict__ p, int n) {
    int i = blockIdx.x * blockDim.x + threadIdx.x;
    if (i < n) p[i] = 0;
}

__global__ void deg_kernel(const int* __restrict__ dst, int* __restrict__ deg, int E) {
    int i = (blockIdx.x * blockDim.x + threadIdx.x) * 4;
    if (i + 3 < E) {
        int4 d = *reinterpret_cast<const int4*>(dst + i);
        atomicAdd(&deg[d.x], 1);
        atomicAdd(&deg[d.y], 1);
        atomicAdd(&deg[d.z], 1);
        atomicAdd(&deg[d.w], 1);
    } else {
        for (int k = i; k < E; ++k) atomicAdd(&deg[dst[k]], 1);
    }
}

__global__ void node_kernel(const float* __restrict__ x, const int* __restrict__ deg,
                            const float* __restrict__ W,
                            float* __restrict__ s, float* __restrict__ dinv,
                            float* __restrict__ acc, int N) {
    int i = blockIdx.x * blockDim.x + threadIdx.x;
    if (i < N) {
        float di = rsqrtf((float)(deg[i] + 1));
        float si = x[i] * W[0] * di;
        dinv[i] = di;
        s[i] = si;
        acc[i] = si;
    }
}

__global__ void scatter_kernel(const int* __restrict__ src, const int* __restrict__ dst,
                               const float* __restrict__ s, float* __restrict__ acc, int E) {
    int i = (blockIdx.x * blockDim.x + threadIdx.x) * 4;
    if (i + 3 < E) {
        int4 sv = *reinterpret_cast<const int4*>(src + i);
        int4 dv = *reinterpret_cast<const int4*>(dst + i);
        atomicAdd(&acc[dv.x], s[sv.x]);
        atomicAdd(&acc[dv.y], s[sv.y]);
        atomicAdd(&acc[dv.z], s[sv.z]);
        atomicAdd(&acc[dv.w], s[sv.w]);
    } else {
        for (int k = i; k < E; ++k) atomicAdd(&acc[dst[k]], s[src[k]]);
    }
}

__global__ void out_kernel(const float* __restrict__ acc, const float* __restrict__ dinv,
                           const float* __restrict__ b, float* __restrict__ out, int N) {
    int i = blockIdx.x * blockDim.x + threadIdx.x;
    if (i < N) {
        float z = dinv[i] * acc[i] + b[0];
        out[i] = 1.0f / (1.0f + expf(-z));
    }
}

extern "C" void kernel_launch(void* const* d_in, const int* in_sizes, int n_in,
                              void* d_out, int out_size, void* d_ws, size_t ws_size,
                              hipStream_t stream) {
    const int N = in_sizes[0];
    const int E = in_sizes[1] / 2;
    const float* x  = (const float*)d_in[0];
    const int*   ei = (const int*)d_in[1];
    const float* W  = (const float*)d_in[2];
    const float* b  = (const float*)d_in[3];
    float* out = (float*)d_out;

    const int* srcp = ei;
    const int* dstp = ei + E;

    const int T = 256;
    const int blocksN = (N + T - 1) / T;
    const int blocksE = ((E + 3) / 4 + T - 1) / T;

    if (ws_size >= (size_t)N * 10 * sizeof(float)) {
        float* copies = (float*)d_ws;
        float* s      = copies + (size_t)8 * N;
        float* dinv   = s + N;

        zero_f_kernel<<<(8 * N + T - 1) / T, T, 0, stream>>>(copies, 8 * N);
        deg_priv_kernel<<<blocksE, T, 0, stream>>>(dstp, copies, E, N);
        node_reduce_kernel<<<blocksN, T, 0, stream>>>(x, W, copies, s, dinv, N);
        scatter_priv_kernel<<<blocksE, T, 0, stream>>>(srcp, dstp, s, copies, E, N);
        out_reduce_kernel<<<blocksN, T, 0, stream>>>(copies, s, dinv, b, out, N);
    } else {
        char* ws = (char*)d_ws;
        int*   deg  = (int*)ws;
        float* s    = (float*)(ws + (size_t)N * 4);
        float* dinv = (float*)(ws + (size_t)N * 8);
        float* acc  = (float*)deg;

        zero_kernel<<<blocksN, T, 0, stream>>>(deg, N);
        deg_kernel<<<blocksE, T, 0, stream>>>(dstp, deg, E);
        node_kernel<<<blocksN, T, 0, stream>>>(x, deg, W, s, dinv, acc, N);
        scatter_kernel<<<blocksE, T, 0, stream>>>(srcp, dstp, s, acc, E);
        out_kernel<<<blocksN, T, 0, stream>>>(acc, dinv, b, out, N);
    }
}

// Round 4
// 840.633 us; speedup vs baseline: 4.0006x; 4.0006x over previous
//
#include <hip/hip_runtime.h>
#include <math.h>

typedef unsigned int u32;
typedef int iv4 __attribute__((ext_vector_type(4)));

#define BKT_BITS 12
#define BKT_SIZE 4096
#define NBMAX    256
#define DEPTH    32          // LDS staging depth per bucket (mean 16/tile)
#define TILE     4096        // edges per block in bin_kernel
#define MSUB     8           // blocks per bucket in deg/agg kernels

// ---------------- fast path kernels ----------------

__global__ void zero_u32(u32* __restrict__ p, int n) {
    int i = blockIdx.x * blockDim.x + threadIdx.x;
    if (i < n) p[i] = 0u;
}

__global__ void count_kernel(const int* __restrict__ dst, u32* __restrict__ gcount, int E, int NB) {
    __shared__ u32 h[NBMAX];
    for (int t = threadIdx.x; t < NBMAX; t += blockDim.x) h[t] = 0u;
    __syncthreads();
    int nvec = E >> 2;
    for (int v = blockIdx.x * blockDim.x + threadIdx.x; v < nvec; v += gridDim.x * blockDim.x) {
        iv4 d = __builtin_nontemporal_load(reinterpret_cast<const iv4*>(dst) + v);
        atomicAdd(&h[((u32)d.x) >> BKT_BITS], 1u);
        atomicAdd(&h[((u32)d.y) >> BKT_BITS], 1u);
        atomicAdd(&h[((u32)d.z) >> BKT_BITS], 1u);
        atomicAdd(&h[((u32)d.w) >> BKT_BITS], 1u);
    }
    if (blockIdx.x == 0) {  // tail
        for (int e = (nvec << 2) + threadIdx.x; e < E; e += blockDim.x)
            atomicAdd(&h[((u32)dst[e]) >> BKT_BITS], 1u);
    }
    __syncthreads();
    for (int t = threadIdx.x; t < NB; t += blockDim.x)
        if (h[t]) atomicAdd(&gcount[t], h[t]);
}

// 1 block, 256 threads: 64-aligned exclusive scan of capacities -> base/cursor
__global__ void scan_kernel(const u32* __restrict__ gcount, u32* __restrict__ gbase,
                            u32* __restrict__ gcursor, int NB) {
    __shared__ u32 sc[NBMAX];
    int t = threadIdx.x;
    u32 cap = 0u;
    if (t < NB) cap = (gcount[t] + 63u) & ~63u;
    sc[t] = cap;
    __syncthreads();
    for (int off = 1; off < NBMAX; off <<= 1) {
        u32 v = (t >= off) ? sc[t - off] : 0u;
        __syncthreads();
        sc[t] += v;
        __syncthreads();
    }
    if (t < NB) {
        u32 base = sc[t] - cap;
        gbase[t]   = base;
        gcursor[t] = base;
    }
}

__global__ void __launch_bounds__(256)
bin_kernel(const int* __restrict__ src, const int* __restrict__ dst,
           u32* __restrict__ recs, u32* __restrict__ gcursor, int E) {
    __shared__ u32 stag[NBMAX * DEPTH];   // 32 KB
    __shared__ u32 scnt[NBMAX];
    for (int t = threadIdx.x; t < NBMAX; t += 256) scnt[t] = 0u;
    __syncthreads();
    int base = blockIdx.x * TILE;
#pragma unroll
    for (int r = 0; r < TILE / 1024; ++r) {
        int v  = (base >> 2) + r * 256 + threadIdx.x;   // int4 index
        int e0 = v << 2;
        if (e0 + 3 < E) {
            iv4 s4 = __builtin_nontemporal_load(reinterpret_cast<const iv4*>(src) + v);
            iv4 d4 = __builtin_nontemporal_load(reinterpret_cast<const iv4*>(dst) + v);
#pragma unroll
            for (int k = 0; k < 4; ++k) {
                u32 ss = (u32)s4[k], dd = (u32)d4[k];
                u32 b   = dd >> BKT_BITS;
                u32 rec = (ss << BKT_BITS) | (dd & (BKT_SIZE - 1));
                u32 slot = atomicAdd(&scnt[b], 1u);
                if (slot < DEPTH) stag[b * DEPTH + slot] = rec;
                else { u32 g = atomicAdd(&gcursor[b], 1u); recs[g] = rec; }  // rare slow path
            }
        } else if (e0 < E) {
            for (int e = e0; e < E && e < e0 + 4; ++e) {
                u32 ss = (u32)src[e], dd = (u32)dst[e];
                u32 b   = dd >> BKT_BITS;
                u32 rec = (ss << BKT_BITS) | (dd & (BKT_SIZE - 1));
                u32 slot = atomicAdd(&scnt[b], 1u);
                if (slot < DEPTH) stag[b * DEPTH + slot] = rec;
                else { u32 g = atomicAdd(&gcursor[b], 1u); recs[g] = rec; }
            }
        }
    }
    __syncthreads();
    // thread t flushes bucket t; each lane's run is contiguous -> L2 merges lines
    int t = threadIdx.x;
    u32 c = scnt[t]; if (c > DEPTH) c = DEPTH;
    if (c > 0u) {
        u32 g = atomicAdd(&gcursor[t], c);
        for (u32 k = 0; k < c; ++k) recs[g + k] = stag[t * DEPTH + k];
    }
}

__global__ void __launch_bounds__(256)
deg_kernel2(const u32* __restrict__ recs, const u32* __restrict__ gbase,
            const u32* __restrict__ gcount, u32* __restrict__ deg) {
    __shared__ u32 cntl[BKT_SIZE];    // 16 KB
    int b = blockIdx.x / MSUB, sub = blockIdx.x % MSUB;
    for (int j = threadIdx.x; j < BKT_SIZE; j += 256) cntl[j] = 0u;
    __syncthreads();
    u32 cnt = gcount[b], base = gbase[b];
    u32 chunk = (cnt + MSUB - 1) / MSUB;
    u32 lo = sub * chunk;
    u32 hi = lo + chunk < cnt ? lo + chunk : cnt;
    for (u32 k = lo + threadIdx.x; k < hi; k += 256) {
        u32 rec = __builtin_nontemporal_load(recs + base + k);
        atomicAdd(&cntl[rec & (BKT_SIZE - 1)], 1u);
    }
    __syncthreads();
    u32* dout = deg + (size_t)b * BKT_SIZE;
    for (int j = threadIdx.x; j < BKT_SIZE; j += 256) {
        u32 v = cntl[j];
        if (v) atomicAdd(&dout[j], v);   // coalesced distinct-address atomics
    }
}

__global__ void node2_kernel(const float* __restrict__ x, const float* __restrict__ W,
                             const u32* __restrict__ deg, float* __restrict__ dinv,
                             float* __restrict__ s, int N) {
    int i = blockIdx.x * blockDim.x + threadIdx.x;
    if (i < N) {
        float di = rsqrtf((float)(deg[i] + 1u));
        dinv[i] = di;
        s[i] = x[i] * W[0] * di;
    }
}

__global__ void __launch_bounds__(256)
agg_kernel(const u32* __restrict__ recs, const u32* __restrict__ gbase,
           const u32* __restrict__ gcount, const float* __restrict__ s,
           float* __restrict__ agg) {
    __shared__ float accl[BKT_SIZE];  // 16 KB
    int b = blockIdx.x / MSUB, sub = blockIdx.x % MSUB;
    for (int j = threadIdx.x; j < BKT_SIZE; j += 256) accl[j] = 0.0f;
    __syncthreads();
    u32 cnt = gcount[b], base = gbase[b];
    u32 chunk = (cnt + MSUB - 1) / MSUB;
    u32 lo = sub * chunk;
    u32 hi = lo + chunk < cnt ? lo + chunk : cnt;
    for (u32 k = lo + threadIdx.x; k < hi; k += 256) {
        u32 rec = __builtin_nontemporal_load(recs + base + k);
        float sv = s[rec >> BKT_BITS];            // cached gather, 4 MB table
        atomicAdd(&accl[rec & (BKT_SIZE - 1)], sv);  // LDS float atomic
    }
    __syncthreads();
    float* aout = agg + (size_t)b * BKT_SIZE;
    for (int j = threadIdx.x; j < BKT_SIZE; j += 256) {
        float v = accl[j];
        if (v != 0.0f) atomicAdd(&aout[j], v);
    }
}

__global__ void out2_kernel(const float* __restrict__ agg, const float* __restrict__ s,
                            const float* __restrict__ dinv, const float* __restrict__ bb,
                            float* __restrict__ out, int N) {
    int i = blockIdx.x * blockDim.x + threadIdx.x;
    if (i < N) {
        float z = dinv[i] * (agg[i] + s[i]) + bb[0];
        out[i] = 1.0f / (1.0f + expf(-z));
    }
}

// ---------------- fallback path (round-1) ----------------
__global__ void zero_kernel(int* __restrict__ p, int n) {
    int i = blockIdx.x * blockDim.x + threadIdx.x;
    if (i < n) p[i] = 0;
}
__global__ void deg_kernel(const int* __restrict__ dst, int* __restrict__ deg, int E) {
    int i = (blockIdx.x * blockDim.x + threadIdx.x) * 4;
    if (i + 3 < E) {
        int4 d = *reinterpret_cast<const int4*>(dst + i);
        atomicAdd(&deg[d.x], 1); atomicAdd(&deg[d.y], 1);
        atomicAdd(&deg[d.z], 1); atomicAdd(&deg[d.w], 1);
    } else {
        for (int k = i; k < E; ++k) atomicAdd(&deg[dst[k]], 1);
    }
}
__global__ void node_kernel(const float* __restrict__ x, const int* __restrict__ deg,
                            const float* __restrict__ W, float* __restrict__ s,
                            float* __restrict__ dinv, float* __restrict__ acc, int N) {
    int i = blockIdx.x * blockDim.x + threadIdx.x;
    if (i < N) {
        float di = rsqrtf((float)(deg[i] + 1));
        float si = x[i] * W[0] * di;
        dinv[i] = di; s[i] = si; acc[i] = si;
    }
}
__global__ void scatter_kernel(const int* __restrict__ src, const int* __restrict__ dst,
                               const float* __restrict__ s, float* __restrict__ acc, int E) {
    int i = (blockIdx.x * blockDim.x + threadIdx.x) * 4;
    if (i + 3 < E) {
        int4 sv = *reinterpret_cast<const int4*>(src + i);
        int4 dv = *reinterpret_cast<const int4*>(dst + i);
        atomicAdd(&acc[dv.x], s[sv.x]); atomicAdd(&acc[dv.y], s[sv.y]);
        atomicAdd(&acc[dv.z], s[sv.z]); atomicAdd(&acc[dv.w], s[sv.w]);
    } else {
        for (int k = i; k < E; ++k) atomicAdd(&acc[dst[k]], s[src[k]]);
    }
}
__global__ void out_kernel(const float* __restrict__ acc, const float* __restrict__ dinv,
                           const float* __restrict__ b, float* __restrict__ out, int N) {
    int i = blockIdx.x * blockDim.x + threadIdx.x;
    if (i < N) {
        float z = dinv[i] * acc[i] + b[0];
        out[i] = 1.0f / (1.0f + expf(-z));
    }
}

extern "C" void kernel_launch(void* const* d_in, const int* in_sizes, int n_in,
                              void* d_out, int out_size, void* d_ws, size_t ws_size,
                              hipStream_t stream) {
    const int N = in_sizes[0];
    const int E = in_sizes[1] / 2;
    const float* x  = (const float*)d_in[0];
    const int*   ei = (const int*)d_in[1];
    const float* W  = (const float*)d_in[2];
    const float* b  = (const float*)d_in[3];
    float* out = (float*)d_out;

    const int* srcp = ei;
    const int* dstp = ei + E;
    const int T = 256;

    const int NB = (N + BKT_SIZE - 1) >> BKT_BITS;          // 245
    const size_t Spad   = (size_t)NB * BKT_SIZE;            // padded node range
    const size_t recCap = (size_t)E + (size_t)NB * 64;      // + alignment slack
    // u32-unit layout: recs | gbase | gcursor | dinv | s | gcount | deg | agg
    const size_t need = (recCap + 2 * (size_t)NB + 2 * (size_t)N + (size_t)NB + 2 * Spad) * 4;

    if (N <= (1 << 20) && NB <= NBMAX && ws_size >= need) {
        u32* p = (u32*)d_ws;
        u32*   recs    = p;                      p += recCap;
        u32*   gbase   = p;                      p += NB;
        u32*   gcursor = p;                      p += NB;
        float* dinv    = (float*)p;              p += N;
        float* s       = (float*)p;              p += N;
        u32*   gcount  = p;                      // zero region start
        u32*   deg     = gcount + NB;
        float* agg     = (float*)(deg + Spad);
        const int zero_n = (int)(NB + 2 * Spad);

        zero_u32<<<(zero_n + T - 1) / T, T, 0, stream>>>(gcount, zero_n);
        count_kernel<<<1024, T, 0, stream>>>(dstp, gcount, E, NB);
        scan_kernel<<<1, T, 0, stream>>>(gcount, gbase, gcursor, NB);
        bin_kernel<<<(E + TILE - 1) / TILE, T, 0, stream>>>(srcp, dstp, recs, gcursor, E);
        deg_kernel2<<<NB * MSUB, T, 0, stream>>>(recs, gbase, gcount, deg);
        node2_kernel<<<(N + T - 1) / T, T, 0, stream>>>(x, W, deg, dinv, s, N);
        agg_kernel<<<NB * MSUB, T, 0, stream>>>(recs, gbase, gcount, s, agg);
        out2_kernel<<<(N + T - 1) / T, T, 0, stream>>>(agg, s, dinv, b, out, N);
    } else {
        char* ws = (char*)d_ws;
        int*   deg  = (int*)ws;
        float* s    = (float*)(ws + (size_t)N * 4);
        float* dinv = (float*)(ws + (size_t)N * 8);
        float* acc  = (float*)deg;
        const int blocksN = (N + T - 1) / T;
        const int blocksE = ((E + 3) / 4 + T - 1) / T;
        zero_kernel<<<blocksN, T, 0, stream>>>(deg, N);
        deg_kernel<<<blocksE, T, 0, stream>>>(dstp, deg, E);
        node_kernel<<<blocksN, T, 0, stream>>>(x, deg, W, s, dinv, acc, N);
        scatter_kernel<<<blocksE, T, 0, stream>>>(srcp, dstp, s, acc, E);
        out_kernel<<<blocksN, T, 0, stream>>>(acc, dinv, b, out, N);
    }
}